// Round 13
// baseline (751.464 us; speedup 1.0000x reference)
//
#include <hip/hip_runtime.h>
#include <hip/hip_bf16.h>

#define EPS 1e-5f
typedef __hip_bfloat16 bf;
typedef __attribute__((ext_vector_type(8))) short bf16x8;
typedef __attribute__((ext_vector_type(4))) short s16x4;
typedef __attribute__((ext_vector_type(4))) float f32x4;

#define MFMA16(a, b, c) __builtin_amdgcn_mfma_f32_16x16x32_bf16(a, b, c, 0, 0, 0)

// Sizes: B=4, C_IN=512, T=4, H=W=K=56, G=8, GP=64, OCH=1024 ; NB=896 ; NP=50176
// ---- ws float offsets ----
#define WS_QSUM     0        // [1024][4]
#define WS_QSQ      4096
#define WS_SIMSUM   8192     // [24][64]
#define WS_SIMSQ    9728
#define WS_OUTSUM   11264    // [1024][8]
#define WS_OUTSQ    19456
#define WS_ZERO_END 27648
#define WS_AQKV     27648
#define WS_BQKV     28672
#define WS_ASIM     29696
#define WS_BSIM     29728
#define WS_AOUT     29760
#define WS_BOUT     30784
// ws bytes: qkP [8][50176][64] bf16 @131072 (51,380,224 B); vP same @51,511,296. total 102.89MB
// d_out scratch: phase A: xbt bf16 [50176][512] @0 ; wb @51,380,224 ; rel tables @73,400,320.
// k4 writes final over d_out.

__device__ __forceinline__ void gload_lds16(const void* g, void* l) {
    __builtin_amdgcn_global_load_lds(
        (const __attribute__((address_space(1))) void*)g,
        (__attribute__((address_space(3))) void*)l, 16, 0, 0);
}
__device__ __forceinline__ float bfbits2f(short b) {
    return __uint_as_float(((uint32_t)(unsigned short)b) << 16);
}
__device__ __forceinline__ short f2bfbits(float f) {
    return (short)__hip_bfloat16_raw(__float2bfloat16(f)).x;
}

// ---------------- K0: x (B,C,T,H,W) f32 -> xbt[p][c] bf16, p = ((b*4+t)*56+w)*56+h ----------------
__global__ __launch_bounds__(256) void k0_transpose(const float* __restrict__ x,
                                                    bf* __restrict__ xbt) {
    int bid = blockIdx.x;                // ((b*4+t)*56 + h)
    int h = bid % 56, bt = bid / 56;
    int b = bt >> 2, t = bt & 3;
    __shared__ short tile[512 * 57];
    const float* src = x + (((size_t)(b * 512) * 4 + t) * 3136) + h * 56;
    for (int e = threadIdx.x; e < 512 * 56; e += 256) {
        int c = e / 56, w = e - c * 56;
        tile[c * 57 + w] = f2bfbits(src[(size_t)c * 12544 + w]);
    }
    __syncthreads();
    short* dst = reinterpret_cast<short*>(xbt);
    size_t pbase = ((size_t)bt * 56) * 56 + h;
    for (int e = threadIdx.x; e < 512 * 56; e += 256) {
        int w = e >> 9, c = e & 511;
        dst[(pbase + (size_t)w * 56) * 512 + c] = tile[c * 57 + w];
    }
}

// ---------------- KW: w f32 [1024][512] -> bf16 ----------------
__global__ __launch_bounds__(256) void kw_conv(const float* __restrict__ w, bf* __restrict__ wb) {
    int i = (blockIdx.x * 256 + threadIdx.x) * 4;
#pragma unroll
    for (int u = 0; u < 4; ++u) wb[i + u] = __float2bfloat16(w[i + u]);
}

// ---------------- KPREP: rel f32 -> relTq/relTk [112][32], relBv [64][128] bf16 ----------------
__global__ __launch_bounds__(256) void kprep(const float* __restrict__ rel,
                                             short* __restrict__ relTq,
                                             short* __restrict__ relTk,
                                             short* __restrict__ relBv) {
    int tid = blockIdx.x * 256 + threadIdx.x;
    if (tid < 3584) {
        int d = tid >> 5, c = tid & 31;
        relTq[tid] = f2bfbits(d < 111 ? rel[c * 111 + d] : 0.f);
        relTk[tid] = f2bfbits(d < 111 ? rel[(32 + c) * 111 + d] : 0.f);
    } else if (tid < 11776) {
        int u = tid - 3584, c = u >> 7, d = u & 127;
        relBv[u] = f2bfbits(d < 111 ? rel[(64 + c) * 111 + d] : 0.f);
    }
}

// ---------------- K1: single-buffer 30KB MFMA GEMM + XOR swizzle, g-fastest grid ----------------
__global__ __launch_bounds__(256) void k1_mfma(const bf* __restrict__ xbt,
                                               const bf* __restrict__ wb,
                                               short* __restrict__ qkP,
                                               short* __restrict__ vP,
                                               float* __restrict__ qsum,
                                               float* __restrict__ qsq) {
    __shared__ __align__(16) short As[8192];   // [128 o][64 c] 16KB, swizzled
    __shared__ __align__(16) short Bs[7168];   // [112 p][64 c] 14KB, swizzled
    int tid = threadIdx.x;
    int g  = blockIdx.x;             // 8 (fastest -> L3 B-sharing)
    int p0 = blockIdx.y * 112;       // 448
    int o0 = g * 128;
    const short* aG = reinterpret_cast<const short*>(wb);
    const short* bG = reinterpret_cast<const short*>(xbt);
    int wv = tid >> 6, l = tid & 63, r16 = l & 15, q4 = l >> 4;

    f32x4 acc[2][7];
#pragma unroll
    for (int i = 0; i < 2; ++i)
#pragma unroll
        for (int j = 0; j < 7; ++j) acc[i][j] = (f32x4){0.f, 0.f, 0.f, 0.f};

    int rowa0 = wv * 32 + r16, rowa1 = rowa0 + 16;

    for (int k0 = 0; k0 < 512; k0 += 64) {
        int ch = tid;
#pragma unroll
        for (int it = 0; it < 4; ++it, ch += 256) {
            int row = ch >> 3, c = ch & 7;
            int gc = (c ^ row) & 7;
            gload_lds16(aG + (((size_t)(o0 + row)) << 9) + k0 + gc * 8, &As[ch << 3]);
        }
        ch = tid;
#pragma unroll
        for (int it = 0; it < 3; ++it, ch += 256) {
            int row = ch >> 3, c = ch & 7;
            int gc = (c ^ row) & 7;
            gload_lds16(bG + (((size_t)(p0 + row)) << 9) + k0 + gc * 8, &Bs[ch << 3]);
        }
        if (tid < 128) {
            int u = tid + 768;
            int row = u >> 3, c = u & 7;
            int gc = (c ^ row) & 7;
            gload_lds16(bG + (((size_t)(p0 + row)) << 9) + k0 + gc * 8, &Bs[u << 3]);
        }
        __syncthreads();
#pragma unroll
        for (int kk = 0; kk < 2; ++kk) {
            int wch = kk * 4 + q4;
            bf16x8 a0 = *reinterpret_cast<const bf16x8*>(&As[rowa0 * 64 + ((wch ^ rowa0) & 7) * 8]);
            bf16x8 a1 = *reinterpret_cast<const bf16x8*>(&As[rowa1 * 64 + ((wch ^ rowa1) & 7) * 8]);
#pragma unroll
            for (int j = 0; j < 7; ++j) {
                int rowb = j * 16 + r16;
                bf16x8 bj = *reinterpret_cast<const bf16x8*>(&Bs[rowb * 64 + ((wch ^ rowb) & 7) * 8]);
                acc[0][j] = MFMA16(a0, bj, acc[0][j]);
                acc[1][j] = MFMA16(a1, bj, acc[1][j]);
            }
        }
        __syncthreads();
    }
    int bkt = blockIdx.y & 3;
#pragma unroll
    for (int i = 0; i < 2; ++i)
#pragma unroll
        for (int r = 0; r < 4; ++r) {
            float sA = 0.f, sB = 0.f;
#pragma unroll
            for (int j = 0; j < 7; ++j) { float v = acc[i][j][r]; sA += v; sB += v * v; }
#pragma unroll
            for (int mk = 1; mk < 16; mk <<= 1) { sA += __shfl_xor(sA, mk); sB += __shfl_xor(sB, mk); }
            if (r16 == 0) {
                int o = o0 + wv * 32 + i * 16 + q4 * 4 + r;
                atomicAdd(&qsum[o * 4 + bkt], sA);
                atomicAdd(&qsq [o * 4 + bkt], sB);
            }
        }
#pragma unroll
    for (int j = 0; j < 7; ++j) {
        int p = p0 + j * 16 + r16;
        size_t rowb = ((size_t)g * 50176 + p) * 64;
#pragma unroll
        for (int i = 0; i < 2; ++i) {
            int op = wv * 32 + i * 16 + q4 * 4;
            s16x4 pk;
#pragma unroll
            for (int r = 0; r < 4; ++r) pk[r] = f2bfbits(acc[i][j][r]);
            short* dst = (op < 64) ? (qkP + rowb + op) : (vP + rowb + (op - 64));
            *reinterpret_cast<s16x4*>(dst) = pk;
        }
    }
}

// ---------------- K1b: bucket reduce -> qkv BN coeffs ----------------
__global__ __launch_bounds__(256) void k1b_coef(const float* __restrict__ qsum, const float* __restrict__ qsq,
                                                const float* __restrict__ gamma, const float* __restrict__ beta,
                                                float* __restrict__ a_c, float* __restrict__ b_c) {
    int o = blockIdx.x * 256 + threadIdx.x;
    float s = qsum[o * 4] + qsum[o * 4 + 1] + qsum[o * 4 + 2] + qsum[o * 4 + 3];
    float s2 = qsq[o * 4] + qsq[o * 4 + 1] + qsq[o * 4 + 2] + qsq[o * 4 + 3];
    float inv = 1.f / 50176.f;
    float mean = s * inv;
    float var = s2 * inv - mean * mean;
    float a = gamma[o] * rsqrtf(var + EPS);
    a_c[o] = a; b_c[o] = beta[o] - a * mean;
}

// ---------------- KBN2: affine v -> vH (in-place) + sim BN stats ----------------
__global__ __launch_bounds__(512) void kbn2(const short* __restrict__ qkP,
                                            short* __restrict__ vP,
                                            const float* __restrict__ aq, const float* __restrict__ bq,
                                            const short* __restrict__ relTq,
                                            const short* __restrict__ relTk,
                                            float* __restrict__ ssum, float* __restrict__ ssq) {
    __shared__ __align__(16) short qkTl[5120];   // [2][64][40]
    __shared__ short vtl[64 * 57];
    __shared__ float red[48];
    int blk = blockIdx.x, n = blk >> 3, g = blk & 7, tid = threadIdx.x;
    size_t sb = ((size_t)g * 50176 + (size_t)n * 56) * 64;
    const short* qsrc = qkP + sb;
    short* vsrc = vP + sb;
    for (int u = tid; u < 448; u += 512) {
        int i = u >> 3, c0 = (u & 7) << 3;
        bf16x8 raw = *reinterpret_cast<const bf16x8*>(qsrc + i * 64 + c0);
        bf16x8 t;
#pragma unroll
        for (int uu = 0; uu < 8; ++uu) {
            int o = g * 128 + c0 + uu;
            t[uu] = f2bfbits(aq[o] * bfbits2f(raw[uu]) + bq[o]);
        }
        *reinterpret_cast<bf16x8*>(&qkTl[((c0 & 32) ? 2560 : 0) + i * 40 + (c0 & 31)]) = t;
    }
    for (int u = tid; u < 640; u += 512) {
        int part = u / 320, r = u - part * 320;
        qkTl[part * 2560 + (56 + r / 40) * 40 + (r % 40)] = 0;
    }
    for (int u = tid; u < 448; u += 512) {
        int i = u >> 3, c0 = (u & 7) << 3;
        bf16x8 raw = *reinterpret_cast<const bf16x8*>(vsrc + i * 64 + c0);
#pragma unroll
        for (int uu = 0; uu < 8; ++uu) {
            int o = g * 128 + 64 + c0 + uu;
            vtl[(c0 + uu) * 57 + i] = f2bfbits(aq[o] * bfbits2f(raw[uu]) + bq[o]);
        }
    }
    __syncthreads();
    for (int u = tid; u < 448; u += 512) {
        int c = u / 7, h0 = (u - c * 7) * 8;
        bf16x8 t;
#pragma unroll
        for (int uu = 0; uu < 8; ++uu) t[uu] = vtl[c * 57 + h0 + uu];
        *reinterpret_cast<bf16x8*>(vsrc + c * 56 + h0) = t;
    }
    // ---- sim BN stats (register MFMA, window-guarded) ----
    int w = tid >> 6, l = tid & 63, m = w >> 1, s = w & 1, la = l & 15, lb = l >> 4;
    bf16x8 aqf = *reinterpret_cast<const bf16x8*>(&qkTl[(m * 16 + la) * 40 + lb * 8]);
    bf16x8 akf = *reinterpret_cast<const bf16x8*>(&qkTl[2560 + (m * 16 + la) * 40 + lb * 8]);
    float s0 = 0, s1 = 0, s2v = 0, q0 = 0, q1 = 0, q2 = 0;
#pragma unroll
    for (int t = 0; t < 2; ++t) {
        int nt = 2 * s + t;
        bf16x8 bk = *reinterpret_cast<const bf16x8*>(&qkTl[2560 + (nt * 16 + la) * 40 + lb * 8]);
        f32x4 acc = {0, 0, 0, 0};
        acc = MFMA16(aqf, bk, acc);
        int j = nt * 16 + la;
        if (j < 56) {
#pragma unroll
            for (int r = 0; r < 4; ++r) {
                int i = m * 16 + lb * 4 + r;
                if (i < 56) { float v = acc[r]; s0 += v; q0 += v * v; }
            }
        }
    }
    int ndt = s ? 3 : 4, dt0 = s * 4;
    for (int t = 0; t < ndt; ++t) {
        int dt = dt0 + t;
        bf16x8 br = *reinterpret_cast<const bf16x8*>(relTq + (dt * 16 + la) * 32 + lb * 8);
        f32x4 acc = {0, 0, 0, 0};
        acc = MFMA16(aqf, br, acc);
        int d = dt * 16 + la;
#pragma unroll
        for (int r = 0; r < 4; ++r) {
            int i = m * 16 + lb * 4 + r;
            if (i < 56 && d >= i && d <= i + 55) { float v = acc[r]; s1 += v; q1 += v * v; }
        }
    }
    for (int t = 0; t < ndt; ++t) {
        int dt = dt0 + t;
        bf16x8 br = *reinterpret_cast<const bf16x8*>(relTk + (dt * 16 + la) * 32 + lb * 8);
        f32x4 acc = {0, 0, 0, 0};
        acc = MFMA16(akf, br, acc);
        int d = dt * 16 + la;
#pragma unroll
        for (int r = 0; r < 4; ++r) {
            int j = m * 16 + lb * 4 + r;
            if (j < 56 && d >= j && d <= j + 55) { float v = acc[r]; s2v += v; q2 += v * v; }
        }
    }
    float vals[6] = {s0, s1, s2v, q0, q1, q2};
#pragma unroll
    for (int v = 0; v < 6; ++v) {
        for (int off = 32; off; off >>= 1) vals[v] += __shfl_down(vals[v], off);
        if (l == 0) red[v * 8 + w] = vals[v];
    }
    __syncthreads();
    if (tid < 6) {
        float tot = 0;
#pragma unroll
        for (int k = 0; k < 8; ++k) tot += red[tid * 8 + k];
        int comp = (tid < 3) ? tid : tid - 3;
        int ch = comp * 8 + g;
        int bkt = blk & 63;
        atomicAdd((tid < 3 ? ssum : ssq) + ch * 64 + bkt, tot);
    }
}

__global__ void k2b_coef(const float* __restrict__ ssum, const float* __restrict__ ssq,
                         const float* __restrict__ gs, const float* __restrict__ bs,
                         float* __restrict__ a_c, float* __restrict__ b_c) {
    int c = threadIdx.x;
    if (c >= 24) return;
    float s = 0, s2 = 0;
    for (int k = 0; k < 64; ++k) { s += ssum[c * 64 + k]; s2 += ssq[c * 64 + k]; }
    float inv = 1.f / 2809856.f;
    float mean = s * inv;
    float var = s2 * inv - mean * mean;
    float a = gs[c] * rsqrtf(var + EPS);
    a_c[c] = a; b_c[c] = bs[c] - a * mean;
}

// ---------------- K3: attention core — scatter-add score assembly (ds_add_f32) ----------------
// LDS (38912 B): qkTl@0 [2][64][40] (10240) | qkl@10240 [56][57] f32 (12768, ends 23008)
//   phase2 overlays: vBl@0 [64][72] (9216) | simB@10240 [64][72] (9216, ends 19456)
//     | Pb@19456 [64][136] (17408, ends 36864)
//   red@36864 (2048) -> total 38912 -> 4 blocks/CU.
// Phase-1: qkl init to bb; MFMA lanes atomicAdd a0*qk / a1*Sq / a2*Kr at sheared targets
// (all three scatter patterns conflict-free). Softmax reads qkl[i*57+l] directly.
__global__ __launch_bounds__(512) void k3_mfma(const short* __restrict__ relTq,
                                               const short* __restrict__ relTk,
                                               const short* __restrict__ relBv,
                                               short* __restrict__ qkP,   // q/k in (rows), sv out
                                               short* __restrict__ vP,    // vH in, sve out
                                               const float* __restrict__ aq, const float* __restrict__ bq,
                                               const float* __restrict__ asim, const float* __restrict__ bsim,
                                               float* __restrict__ osum, float* __restrict__ osq) {
    __shared__ __align__(16) char smem[38912];
    short* qkTl = (short*)smem;                 // [2][64][40] ; phase2: vBl [64][72]
    float* qkl  = (float*)(smem + 10240);       // [56][57] f32
    short* simB = (short*)(smem + 10240);       // phase2 overlay [64][72]
    short* Pb   = (short*)(smem + 19456);       // phase2 overlay [64][136]
    short* vBl  = (short*)smem;
    float* red  = (float*)(smem + 36864);

    int blk = blockIdx.x, n = blk >> 3, g = blk & 7, tid = threadIdx.x;
    size_t sb = ((size_t)g * 50176 + (size_t)n * 56) * 64;
    short* svdst = qkP + sb;
    short* vHs   = vP + sb;

    float a0 = asim[g], a1 = asim[8 + g], a2 = asim[16 + g];
    float bb = bsim[g] + bsim[8 + g] + bsim[16 + g];

    // T14: issue vH global load early (held in regs until after phase-1 barrier)
    bf16x8 vreg = {0, 0, 0, 0, 0, 0, 0, 0};
    int vc = tid / 7, vch = tid - vc * 7;       // valid for tid < 448
    if (tid < 448)
        vreg = *reinterpret_cast<const bf16x8*>(vHs + vc * 56 + vch * 8);

    // stage q/k rows with inline BN affine -> qkTl[part][i][40]
    for (int u = tid; u < 448; u += 512) {
        int i = u >> 3, c0 = (u & 7) << 3;
        bf16x8 raw = *reinterpret_cast<const bf16x8*>(svdst + i * 64 + c0);
        bf16x8 t;
#pragma unroll
        for (int uu = 0; uu < 8; ++uu) {
            int o = g * 128 + c0 + uu;
            t[uu] = f2bfbits(aq[o] * bfbits2f(raw[uu]) + bq[o]);
        }
        *reinterpret_cast<bf16x8*>(&qkTl[((c0 & 32) ? 2560 : 0) + i * 40 + (c0 & 31)]) = t;
    }
    for (int u = tid; u < 640; u += 512) {
        int part = u / 320, r = u - part * 320;
        qkTl[part * 2560 + (56 + r / 40) * 40 + (r % 40)] = 0;
    }
    // init score buffer to combined bias
    for (int e = tid; e < 3192; e += 512) qkl[e] = bb;
    __syncthreads();

    int w = tid >> 6, l = tid & 63, m = w >> 1, s = w & 1, la = l & 15, lb = l >> 4;
    int i0 = m * 16 + lb * 4;                   // 4-aligned row base
    {
        bf16x8 aqf = *reinterpret_cast<const bf16x8*>(&qkTl[(m * 16 + la) * 40 + lb * 8]);
        bf16x8 akf = *reinterpret_cast<const bf16x8*>(&qkTl[(64 + m * 16 + la) * 40 + lb * 8]);
        __builtin_amdgcn_s_setprio(1);
        // qk: scatter-add a0*qk[i][j]   (j = nt*16+la: consecutive per la -> conflict-free)
#pragma unroll
        for (int t = 0; t < 2; ++t) {
            int nt = 2 * s + t;
            bf16x8 bk = *reinterpret_cast<const bf16x8*>(&qkTl[(64 + nt * 16 + la) * 40 + lb * 8]);
            f32x4 acc = {0, 0, 0, 0};
            acc = MFMA16(aqf, bk, acc);
            int j = nt * 16 + la;
            if (j < 56) {
#pragma unroll
                for (int r = 0; r < 4; ++r) {
                    int i = i0 + r;
                    if (i < 56) atomicAdd(&qkl[i * 57 + j], a0 * acc[r]);
                }
            }
        }
        int ndt = s ? 3 : 4, dt0 = s * 4;
        // Sq: lane (i,d) -> qkl[i][i-d+55]  (j = const - la: conflict-free)
        for (int t = 0; t < ndt; ++t) {
            int dt = dt0 + t;
            bf16x8 br = *reinterpret_cast<const bf16x8*>(relTq + (dt * 16 + la) * 32 + lb * 8);
            f32x4 acc = {0, 0, 0, 0};
            acc = MFMA16(aqf, br, acc);
            int d = dt * 16 + la;
#pragma unroll
            for (int r = 0; r < 4; ++r) {
                int i = i0 + r;
                if (i < 56 && d >= i && d <= i + 55)
                    atomicAdd(&qkl[i * 57 + (i - d + 55)], a1 * acc[r]);
            }
        }
        // Kr: lane (jj,d) -> qkl[jj-d+55][jj]  (i stride 57 words == 25 mod 32, gcd 1: conflict-free)
        for (int t = 0; t < ndt; ++t) {
            int dt = dt0 + t;
            bf16x8 br = *reinterpret_cast<const bf16x8*>(relTk + (dt * 16 + la) * 32 + lb * 8);
            f32x4 acc = {0, 0, 0, 0};
            acc = MFMA16(akf, br, acc);
            int d = dt * 16 + la;
#pragma unroll
            for (int r = 0; r < 4; ++r) {
                int jj = i0 + r;
                if (jj < 56 && d >= jj && d <= jj + 55)
                    atomicAdd(&qkl[(jj - d + 55) * 57 + jj], a2 * acc[r]);
            }
        }
        __builtin_amdgcn_s_setprio(0);
    }
    __syncthreads();

    // write pre-loaded vH regs into vBl (qkTl region dead now); zero pad cols 56..71
    if (tid < 448)
        *reinterpret_cast<bf16x8*>(&vBl[vc * 72 + vch * 8]) = vreg;
    if (tid < 128) {
        int c = tid >> 1, chp = tid & 1;
        bf16x8 z = {0, 0, 0, 0, 0, 0, 0, 0};
        *reinterpret_cast<bf16x8*>(&vBl[c * 72 + 56 + chp * 8]) = z;
    }
    // softmax (scores fully assembled in qkl)
    float p[7];
#pragma unroll
    for (int rr = 0; rr < 7; ++rr) {
        int i = w * 7 + rr;
        float sc = (l < 56) ? qkl[i * 57 + l] : -1e30f;
        float mx = sc;
#pragma unroll
        for (int off = 32; off; off >>= 1) mx = fmaxf(mx, __shfl_xor(mx, off));
        float e = (l < 56) ? __expf(sc - mx) : 0.f;
        float su = e;
#pragma unroll
        for (int off = 32; off; off >>= 1) su += __shfl_xor(su, off);
        p[rr] = e / su;
    }
    __syncthreads();   // qkl reads done

#pragma unroll
    for (int rr = 0; rr < 7; ++rr) {
        int i = w * 7 + rr;
        short pv = f2bfbits(p[rr]);
        simB[i * 72 + l] = (l < 56) ? pv : (short)0;
        if (l < 56) Pb[i * 136 + (i - l + 55)] = pv;
        if (l < i || l > i + 55) Pb[i * 136 + l] = 0;
        if (l > i - 9) Pb[i * 136 + l + 64] = 0;
        if (l < 8) Pb[i * 136 + l + 128] = 0;
    }
    __syncthreads();

    // phase 2: sv = v . P^T ; sve = rel_v . Pskew^T
    f32x4 sva[2]  = {{0, 0, 0, 0}, {0, 0, 0, 0}};
    f32x4 svea[2] = {{0, 0, 0, 0}, {0, 0, 0, 0}};
    __builtin_amdgcn_s_setprio(1);
#pragma unroll
    for (int ks = 0; ks < 2; ++ks) {
        bf16x8 av = *reinterpret_cast<const bf16x8*>(&vBl[(m * 16 + la) * 72 + ks * 32 + lb * 8]);
#pragma unroll
        for (int t = 0; t < 2; ++t) {
            int nt = 2 * s + t;
            bf16x8 bsf = *reinterpret_cast<const bf16x8*>(&simB[(nt * 16 + la) * 72 + ks * 32 + lb * 8]);
            sva[t] = MFMA16(av, bsf, sva[t]);
        }
    }
#pragma unroll
    for (int ks = 0; ks < 4; ++ks) {
        bf16x8 ar = *reinterpret_cast<const bf16x8*>(relBv + (m * 16 + la) * 128 + ks * 32 + lb * 8);
#pragma unroll
        for (int t = 0; t < 2; ++t) {
            int nt = 2 * s + t;
            bf16x8 bp = *reinterpret_cast<const bf16x8*>(&Pb[(nt * 16 + la) * 136 + ks * 32 + lb * 8]);
            svea[t] = MFMA16(ar, bp, svea[t]);
        }
    }
    __builtin_amdgcn_s_setprio(0);
    // store sv -> qkP slice, sve -> vP slice (both dead) + out-BN partial stats
    float st0[4] = {0, 0, 0, 0}, st1[4] = {0, 0, 0, 0}, st2[4] = {0, 0, 0, 0}, st3[4] = {0, 0, 0, 0};
#pragma unroll
    for (int t = 0; t < 2; ++t) {
        int i = (2 * s + t) * 16 + la;
        bool ok = i < 56;
#pragma unroll
        for (int r = 0; r < 4; ++r) {
            int c = m * 16 + lb * 4 + r;
            float va = sva[t][r], ve = svea[t][r];
            if (ok) {
                svdst[c * 56 + i] = f2bfbits(va);
                vHs  [c * 56 + i] = f2bfbits(ve);
                st0[r] += va; st1[r] += va * va; st2[r] += ve; st3[r] += ve * ve;
            }
        }
    }
#pragma unroll
    for (int r = 0; r < 4; ++r) {
#pragma unroll
        for (int mk = 1; mk < 16; mk <<= 1) {
            st0[r] += __shfl_xor(st0[r], mk);
            st1[r] += __shfl_xor(st1[r], mk);
            st2[r] += __shfl_xor(st2[r], mk);
            st3[r] += __shfl_xor(st3[r], mk);
        }
    }
    __syncthreads();   // all Pb/simB reads done before red overlay region writes
    if (la == 0) {
#pragma unroll
        for (int r = 0; r < 4; ++r) {
            int c = m * 16 + lb * 4 + r;
            red[(0 * 64 + c) * 2 + s] = st0[r];
            red[(1 * 64 + c) * 2 + s] = st1[r];
            red[(2 * 64 + c) * 2 + s] = st2[r];
            red[(3 * 64 + c) * 2 + s] = st3[r];
        }
    }
    __syncthreads();
    if (tid < 64) {
        int c = tid, o2 = (g * 64 + c) * 2, bkt = blk & 7;
        atomicAdd(&osum[o2 * 8 + bkt],       red[(0 * 64 + c) * 2] + red[(0 * 64 + c) * 2 + 1]);
        atomicAdd(&osq [o2 * 8 + bkt],       red[(1 * 64 + c) * 2] + red[(1 * 64 + c) * 2 + 1]);
        atomicAdd(&osum[(o2 + 1) * 8 + bkt], red[(2 * 64 + c) * 2] + red[(2 * 64 + c) * 2 + 1]);
        atomicAdd(&osq [(o2 + 1) * 8 + bkt], red[(3 * 64 + c) * 2] + red[(3 * 64 + c) * 2 + 1]);
    }
}

__global__ __launch_bounds__(256) void k3b_coef(const float* __restrict__ osum, const float* __restrict__ osq,
                                                const float* __restrict__ go, const float* __restrict__ bo,
                                                float* __restrict__ a_c, float* __restrict__ b_c) {
    int o = blockIdx.x * 256 + threadIdx.x;
    float s = 0, s2 = 0;
#pragma unroll
    for (int k = 0; k < 8; ++k) { s += osum[o * 8 + k]; s2 += osq[o * 8 + k]; }
    float inv = 1.f / 50176.f;
    float mean = s * inv;
    float var = s2 * inv - mean * mean;
    float a = go[o] * rsqrtf(var + EPS);
    a_c[o] = a; b_c[o] = bo[o] - a * mean;
}

// ---------------- K4: out BN + pair-sum + transpose to (B,OUT,T,H,W) ----------------
__global__ __launch_bounds__(256) void k4_out(const short* __restrict__ svq,
                                              const short* __restrict__ sve,
                                              const float* __restrict__ ao, const float* __restrict__ bo,
                                              float* __restrict__ out) {
    int blk = blockIdx.x;
    int oc = blk & 511, bt = blk >> 9;
    int b = bt >> 2, tt = bt & 3;
    int g = oc >> 6, c = oc & 63;
    __shared__ float tile[56][57];
    int tid = threadIdx.x;
    int o_sv = oc * 2, o_sve = oc * 2 + 1;
    float asv = ao[o_sv], bsv = bo[o_sv], asve = ao[o_sve], bsve = bo[o_sve];
    float badd = bsv + bsve;
    int nbase = (b * 4 + tt) * 56;
    for (int e = tid; e < 3136; e += 256) {
        int wq = e / 56, h = e - wq * 56;
        size_t idx = ((size_t)g * 50176 + (size_t)(nbase + wq) * 56) * 64 + c * 56 + h;
        tile[wq][h] = asv * bfbits2f(svq[idx]) + asve * bfbits2f(sve[idx]) + badd;
    }
    __syncthreads();
    size_t ob = ((size_t)(b * 512 + oc) * 4 + tt) * 3136;
    for (int e = tid; e < 3136; e += 256) {
        int h = e / 56, wq = e - h * 56;
        out[ob + h * 56 + wq] = tile[wq][h];
    }
}

extern "C" void kernel_launch(void* const* d_in, const int* in_sizes, int n_in,
                              void* d_out, int out_size, void* d_ws, size_t ws_size,
                              hipStream_t stream) {
    (void)in_sizes; (void)n_in; (void)out_size; (void)ws_size;
    const float* x     = (const float*)d_in[0];
    const float* w_qkv = (const float*)d_in[1];
    const float* g_qkv = (const float*)d_in[2];
    const float* b_qkv = (const float*)d_in[3];
    const float* rel   = (const float*)d_in[4];
    const float* g_sim = (const float*)d_in[5];
    const float* b_sim = (const float*)d_in[6];
    const float* g_out = (const float*)d_in[7];
    const float* b_out = (const float*)d_in[8];
    float* ws  = (float*)d_ws;
    float* out = (float*)d_out;
    short* qkP = (short*)((char*)d_ws + 131072);      // [8][50176][64] bf16 (51.4MB)
    short* vP  = (short*)((char*)d_ws + 51511296);    // [8][50176][64] bf16 (51.4MB)
    bf*    xbt = (bf*)d_out;                          // [50176][512] bf16, dead after k1
    bf*    wb  = (bf*)((char*)d_out + 51380224);      // [1024][512] bf16
    short* relTq = (short*)((char*)d_out + 73400320);
    short* relTk = relTq + 3584;
    short* relBv = relTk + 3584;                      // [64][128]

    hipMemsetAsync(ws, 0, WS_ZERO_END * sizeof(float), stream);
    k0_transpose<<<896, 256, 0, stream>>>(x, xbt);
    kw_conv<<<512, 256, 0, stream>>>(w_qkv, wb);
    kprep<<<46, 256, 0, stream>>>(rel, relTq, relTk, relBv);
    k1_mfma<<<dim3(8, 448), 256, 0, stream>>>(xbt, wb, qkP, vP, ws + WS_QSUM, ws + WS_QSQ);
    k1b_coef<<<4, 256, 0, stream>>>(ws + WS_QSUM, ws + WS_QSQ, g_qkv, b_qkv,
                                    ws + WS_AQKV, ws + WS_BQKV);
    kbn2<<<7168, 512, 0, stream>>>(qkP, vP, ws + WS_AQKV, ws + WS_BQKV,
                                   relTq, relTk, ws + WS_SIMSUM, ws + WS_SIMSQ);
    k2b_coef<<<1, 64, 0, stream>>>(ws + WS_SIMSUM, ws + WS_SIMSQ, g_sim, b_sim,
                                   ws + WS_ASIM, ws + WS_BSIM);
    k3_mfma<<<7168, 512, 0, stream>>>(relTq, relTk, relBv, qkP, vP,
                                      ws + WS_AQKV, ws + WS_BQKV,
                                      ws + WS_ASIM, ws + WS_BSIM,
                                      ws + WS_OUTSUM, ws + WS_OUTSQ);
    k3b_coef<<<4, 256, 0, stream>>>(ws + WS_OUTSUM, ws + WS_OUTSQ, g_out, b_out,
                                    ws + WS_AOUT, ws + WS_BOUT);
    k4_out<<<8192, 256, 0, stream>>>(qkP, vP, ws + WS_AOUT, ws + WS_BOUT, out);
}

// Round 14
// 441.432 us; speedup vs baseline: 1.7023x; 1.7023x over previous
//
#include <hip/hip_runtime.h>
#include <hip/hip_bf16.h>

#define EPS 1e-5f
typedef __hip_bfloat16 bf;
typedef __attribute__((ext_vector_type(8))) short bf16x8;
typedef __attribute__((ext_vector_type(4))) short s16x4;
typedef __attribute__((ext_vector_type(4))) float f32x4;

#define MFMA16(a, b, c) __builtin_amdgcn_mfma_f32_16x16x32_bf16(a, b, c, 0, 0, 0)

// Sizes: B=4, C_IN=512, T=4, H=W=K=56, G=8, GP=64, OCH=1024 ; NB=896 ; NP=50176
#define WS_QSUM     0
#define WS_QSQ      4096
#define WS_SIMSUM   8192
#define WS_SIMSQ    9728
#define WS_OUTSUM   11264
#define WS_OUTSQ    19456
#define WS_ZERO_END 27648
#define WS_AQKV     27648
#define WS_BQKV     28672
#define WS_ASIM     29696
#define WS_BSIM     29728
#define WS_AOUT     29760
#define WS_BOUT     30784
// ws bytes: qkP [8][50176][64] bf16 @131072; vP same @51,511,296. total 102.89MB
// d_out scratch: xbt bf16 [50176][512] @0 ; wb @51,380,224 ; rel tables @73,400,320.

__device__ __forceinline__ void gload_lds16(const void* g, void* l) {
    __builtin_amdgcn_global_load_lds(
        (const __attribute__((address_space(1))) void*)g,
        (__attribute__((address_space(3))) void*)l, 16, 0, 0);
}
__device__ __forceinline__ float bfbits2f(short b) {
    return __uint_as_float(((uint32_t)(unsigned short)b) << 16);
}
__device__ __forceinline__ short f2bfbits(float f) {
    return (short)__hip_bfloat16_raw(__float2bfloat16(f)).x;
}

// ---------------- K0 ----------------
__global__ __launch_bounds__(256) void k0_transpose(const float* __restrict__ x,
                                                    bf* __restrict__ xbt) {
    int bid = blockIdx.x;
    int h = bid % 56, bt = bid / 56;
    int b = bt >> 2, t = bt & 3;
    __shared__ short tile[512 * 57];
    const float* src = x + (((size_t)(b * 512) * 4 + t) * 3136) + h * 56;
    for (int e = threadIdx.x; e < 512 * 56; e += 256) {
        int c = e / 56, w = e - c * 56;
        tile[c * 57 + w] = f2bfbits(src[(size_t)c * 12544 + w]);
    }
    __syncthreads();
    short* dst = reinterpret_cast<short*>(xbt);
    size_t pbase = ((size_t)bt * 56) * 56 + h;
    for (int e = threadIdx.x; e < 512 * 56; e += 256) {
        int w = e >> 9, c = e & 511;
        dst[(pbase + (size_t)w * 56) * 512 + c] = tile[c * 57 + w];
    }
}

// ---------------- KW ----------------
__global__ __launch_bounds__(256) void kw_conv(const float* __restrict__ w, bf* __restrict__ wb) {
    int i = (blockIdx.x * 256 + threadIdx.x) * 4;
#pragma unroll
    for (int u = 0; u < 4; ++u) wb[i + u] = __float2bfloat16(w[i + u]);
}

// ---------------- KPREP ----------------
__global__ __launch_bounds__(256) void kprep(const float* __restrict__ rel,
                                             short* __restrict__ relTq,
                                             short* __restrict__ relTk,
                                             short* __restrict__ relBv) {
    int tid = blockIdx.x * 256 + threadIdx.x;
    if (tid < 3584) {
        int d = tid >> 5, c = tid & 31;
        relTq[tid] = f2bfbits(d < 111 ? rel[c * 111 + d] : 0.f);
        relTk[tid] = f2bfbits(d < 111 ? rel[(32 + c) * 111 + d] : 0.f);
    } else if (tid < 11776) {
        int u = tid - 3584, c = u >> 7, d = u & 127;
        relBv[u] = f2bfbits(d < 111 ? rel[(64 + c) * 111 + d] : 0.f);
    }
}

// ---------------- K1: single-buffer 30KB MFMA GEMM + XOR swizzle, g-fastest grid ----------------
__global__ __launch_bounds__(256) void k1_mfma(const bf* __restrict__ xbt,
                                               const bf* __restrict__ wb,
                                               short* __restrict__ qkP,
                                               short* __restrict__ vP,
                                               float* __restrict__ qsum,
                                               float* __restrict__ qsq) {
    __shared__ __align__(16) short As[8192];
    __shared__ __align__(16) short Bs[7168];
    int tid = threadIdx.x;
    int g  = blockIdx.x;
    int p0 = blockIdx.y * 112;
    int o0 = g * 128;
    const short* aG = reinterpret_cast<const short*>(wb);
    const short* bG = reinterpret_cast<const short*>(xbt);
    int wv = tid >> 6, l = tid & 63, r16 = l & 15, q4 = l >> 4;

    f32x4 acc[2][7];
#pragma unroll
    for (int i = 0; i < 2; ++i)
#pragma unroll
        for (int j = 0; j < 7; ++j) acc[i][j] = (f32x4){0.f, 0.f, 0.f, 0.f};

    int rowa0 = wv * 32 + r16, rowa1 = rowa0 + 16;

    for (int k0 = 0; k0 < 512; k0 += 64) {
        int ch = tid;
#pragma unroll
        for (int it = 0; it < 4; ++it, ch += 256) {
            int row = ch >> 3, c = ch & 7;
            int gc = (c ^ row) & 7;
            gload_lds16(aG + (((size_t)(o0 + row)) << 9) + k0 + gc * 8, &As[ch << 3]);
        }
        ch = tid;
#pragma unroll
        for (int it = 0; it < 3; ++it, ch += 256) {
            int row = ch >> 3, c = ch & 7;
            int gc = (c ^ row) & 7;
            gload_lds16(bG + (((size_t)(p0 + row)) << 9) + k0 + gc * 8, &Bs[ch << 3]);
        }
        if (tid < 128) {
            int u = tid + 768;
            int row = u >> 3, c = u & 7;
            int gc = (c ^ row) & 7;
            gload_lds16(bG + (((size_t)(p0 + row)) << 9) + k0 + gc * 8, &Bs[u << 3]);
        }
        __syncthreads();
#pragma unroll
        for (int kk = 0; kk < 2; ++kk) {
            int wch = kk * 4 + q4;
            bf16x8 a0 = *reinterpret_cast<const bf16x8*>(&As[rowa0 * 64 + ((wch ^ rowa0) & 7) * 8]);
            bf16x8 a1 = *reinterpret_cast<const bf16x8*>(&As[rowa1 * 64 + ((wch ^ rowa1) & 7) * 8]);
#pragma unroll
            for (int j = 0; j < 7; ++j) {
                int rowb = j * 16 + r16;
                bf16x8 bj = *reinterpret_cast<const bf16x8*>(&Bs[rowb * 64 + ((wch ^ rowb) & 7) * 8]);
                acc[0][j] = MFMA16(a0, bj, acc[0][j]);
                acc[1][j] = MFMA16(a1, bj, acc[1][j]);
            }
        }
        __syncthreads();
    }
    int bkt = blockIdx.y & 3;
#pragma unroll
    for (int i = 0; i < 2; ++i)
#pragma unroll
        for (int r = 0; r < 4; ++r) {
            float sA = 0.f, sB = 0.f;
#pragma unroll
            for (int j = 0; j < 7; ++j) { float v = acc[i][j][r]; sA += v; sB += v * v; }
#pragma unroll
            for (int mk = 1; mk < 16; mk <<= 1) { sA += __shfl_xor(sA, mk); sB += __shfl_xor(sB, mk); }
            if (r16 == 0) {
                int o = o0 + wv * 32 + i * 16 + q4 * 4 + r;
                atomicAdd(&qsum[o * 4 + bkt], sA);
                atomicAdd(&qsq [o * 4 + bkt], sB);
            }
        }
#pragma unroll
    for (int j = 0; j < 7; ++j) {
        int p = p0 + j * 16 + r16;
        size_t rowb = ((size_t)g * 50176 + p) * 64;
#pragma unroll
        for (int i = 0; i < 2; ++i) {
            int op = wv * 32 + i * 16 + q4 * 4;
            s16x4 pk;
#pragma unroll
            for (int r = 0; r < 4; ++r) pk[r] = f2bfbits(acc[i][j][r]);
            short* dst = (op < 64) ? (qkP + rowb + op) : (vP + rowb + (op - 64));
            *reinterpret_cast<s16x4*>(dst) = pk;
        }
    }
}

// ---------------- K1b ----------------
__global__ __launch_bounds__(256) void k1b_coef(const float* __restrict__ qsum, const float* __restrict__ qsq,
                                                const float* __restrict__ gamma, const float* __restrict__ beta,
                                                float* __restrict__ a_c, float* __restrict__ b_c) {
    int o = blockIdx.x * 256 + threadIdx.x;
    float s = qsum[o * 4] + qsum[o * 4 + 1] + qsum[o * 4 + 2] + qsum[o * 4 + 3];
    float s2 = qsq[o * 4] + qsq[o * 4 + 1] + qsq[o * 4 + 2] + qsq[o * 4 + 3];
    float inv = 1.f / 50176.f;
    float mean = s * inv;
    float var = s2 * inv - mean * mean;
    float a = gamma[o] * rsqrtf(var + EPS);
    a_c[o] = a; b_c[o] = beta[o] - a * mean;
}

// ---------------- KBN2: affine v -> vH (in-place) + sim BN stats ----------------
__global__ __launch_bounds__(512) void kbn2(const short* __restrict__ qkP,
                                            short* __restrict__ vP,
                                            const float* __restrict__ aq, const float* __restrict__ bq,
                                            const short* __restrict__ relTq,
                                            const short* __restrict__ relTk,
                                            float* __restrict__ ssum, float* __restrict__ ssq) {
    __shared__ __align__(16) short qkTl[5120];
    __shared__ short vtl[64 * 57];
    __shared__ float red[48];
    int blk = blockIdx.x, n = blk >> 3, g = blk & 7, tid = threadIdx.x;
    size_t sb = ((size_t)g * 50176 + (size_t)n * 56) * 64;
    const short* qsrc = qkP + sb;
    short* vsrc = vP + sb;
    for (int u = tid; u < 448; u += 512) {
        int i = u >> 3, c0 = (u & 7) << 3;
        bf16x8 raw = *reinterpret_cast<const bf16x8*>(qsrc + i * 64 + c0);
        bf16x8 t;
#pragma unroll
        for (int uu = 0; uu < 8; ++uu) {
            int o = g * 128 + c0 + uu;
            t[uu] = f2bfbits(aq[o] * bfbits2f(raw[uu]) + bq[o]);
        }
        *reinterpret_cast<bf16x8*>(&qkTl[((c0 & 32) ? 2560 : 0) + i * 40 + (c0 & 31)]) = t;
    }
    for (int u = tid; u < 640; u += 512) {
        int part = u / 320, r = u - part * 320;
        qkTl[part * 2560 + (56 + r / 40) * 40 + (r % 40)] = 0;
    }
    for (int u = tid; u < 448; u += 512) {
        int i = u >> 3, c0 = (u & 7) << 3;
        bf16x8 raw = *reinterpret_cast<const bf16x8*>(vsrc + i * 64 + c0);
#pragma unroll
        for (int uu = 0; uu < 8; ++uu) {
            int o = g * 128 + 64 + c0 + uu;
            vtl[(c0 + uu) * 57 + i] = f2bfbits(aq[o] * bfbits2f(raw[uu]) + bq[o]);
        }
    }
    __syncthreads();
    for (int u = tid; u < 448; u += 512) {
        int c = u / 7, h0 = (u - c * 7) * 8;
        bf16x8 t;
#pragma unroll
        for (int uu = 0; uu < 8; ++uu) t[uu] = vtl[c * 57 + h0 + uu];
        *reinterpret_cast<bf16x8*>(vsrc + c * 56 + h0) = t;
    }
    int w = tid >> 6, l = tid & 63, m = w >> 1, s = w & 1, la = l & 15, lb = l >> 4;
    bf16x8 aqf = *reinterpret_cast<const bf16x8*>(&qkTl[(m * 16 + la) * 40 + lb * 8]);
    bf16x8 akf = *reinterpret_cast<const bf16x8*>(&qkTl[2560 + (m * 16 + la) * 40 + lb * 8]);
    float s0 = 0, s1 = 0, s2v = 0, q0 = 0, q1 = 0, q2 = 0;
#pragma unroll
    for (int t = 0; t < 2; ++t) {
        int nt = 2 * s + t;
        bf16x8 bk = *reinterpret_cast<const bf16x8*>(&qkTl[2560 + (nt * 16 + la) * 40 + lb * 8]);
        f32x4 acc = {0, 0, 0, 0};
        acc = MFMA16(aqf, bk, acc);
        int j = nt * 16 + la;
        if (j < 56) {
#pragma unroll
            for (int r = 0; r < 4; ++r) {
                int i = m * 16 + lb * 4 + r;
                if (i < 56) { float v = acc[r]; s0 += v; q0 += v * v; }
            }
        }
    }
    int ndt = s ? 3 : 4, dt0 = s * 4;
    for (int t = 0; t < ndt; ++t) {
        int dt = dt0 + t;
        bf16x8 br = *reinterpret_cast<const bf16x8*>(relTq + (dt * 16 + la) * 32 + lb * 8);
        f32x4 acc = {0, 0, 0, 0};
        acc = MFMA16(aqf, br, acc);
        int d = dt * 16 + la;
#pragma unroll
        for (int r = 0; r < 4; ++r) {
            int i = m * 16 + lb * 4 + r;
            if (i < 56 && d >= i && d <= i + 55) { float v = acc[r]; s1 += v; q1 += v * v; }
        }
    }
    for (int t = 0; t < ndt; ++t) {
        int dt = dt0 + t;
        bf16x8 br = *reinterpret_cast<const bf16x8*>(relTk + (dt * 16 + la) * 32 + lb * 8);
        f32x4 acc = {0, 0, 0, 0};
        acc = MFMA16(akf, br, acc);
        int d = dt * 16 + la;
#pragma unroll
        for (int r = 0; r < 4; ++r) {
            int j = m * 16 + lb * 4 + r;
            if (j < 56 && d >= j && d <= j + 55) { float v = acc[r]; s2v += v; q2 += v * v; }
        }
    }
    float vals[6] = {s0, s1, s2v, q0, q1, q2};
#pragma unroll
    for (int v = 0; v < 6; ++v) {
        for (int off = 32; off; off >>= 1) vals[v] += __shfl_down(vals[v], off);
        if (l == 0) red[v * 8 + w] = vals[v];
    }
    __syncthreads();
    if (tid < 6) {
        float tot = 0;
#pragma unroll
        for (int k = 0; k < 8; ++k) tot += red[tid * 8 + k];
        int comp = (tid < 3) ? tid : tid - 3;
        int ch = comp * 8 + g;
        int bkt = blk & 63;
        atomicAdd((tid < 3 ? ssum : ssq) + ch * 64 + bkt, tot);
    }
}

__global__ void k2b_coef(const float* __restrict__ ssum, const float* __restrict__ ssq,
                         const float* __restrict__ gs, const float* __restrict__ bs,
                         float* __restrict__ a_c, float* __restrict__ b_c) {
    int c = threadIdx.x;
    if (c >= 24) return;
    float s = 0, s2 = 0;
    for (int k = 0; k < 64; ++k) { s += ssum[c * 64 + k]; s2 += ssq[c * 64 + k]; }
    float inv = 1.f / 2809856.f;
    float mean = s * inv;
    float var = s2 * inv - mean * mean;
    float a = gs[c] * rsqrtf(var + EPS);
    a_c[c] = a; b_c[c] = bs[c] - a * mean;
}

// ---------------- K3: attention core — race-free += score assembly (no atomics) ----------------
// LDS (38912 B): qkTl@0 [2][64][40] (10240) | qkl@10240 [56][57] f32 (12768, ends 23008)
//   phase2 overlays: vBl@0 [64][72] | simB@10240 [64][72] | Pb@19456 [64][136] (ends 36864)
//   red@36864 (2048) -> 38912 total -> 4+ blocks/CU.
// Score terms applied as three barrier-separated += passes (each internally write-unique,
// plain ds ops, conflict-light). Softmax: no-max (BN-bounded scores), rcp divide.
__global__ __launch_bounds__(512) void k3_mfma(const short* __restrict__ relTq,
                                               const short* __restrict__ relTk,
                                               const short* __restrict__ relBv,
                                               short* __restrict__ qkP,   // q/k in (rows), sv out
                                               short* __restrict__ vP,    // vH in, sve out
                                               const float* __restrict__ aq, const float* __restrict__ bq,
                                               const float* __restrict__ asim, const float* __restrict__ bsim,
                                               float* __restrict__ osum, float* __restrict__ osq) {
    __shared__ __align__(16) char smem[38912];
    short* qkTl = (short*)smem;                 // [2][64][40] ; phase2: vBl [64][72]
    float* qkl  = (float*)(smem + 10240);       // [56][57] f32
    short* simB = (short*)(smem + 10240);       // phase2 overlay
    short* Pb   = (short*)(smem + 19456);       // phase2 overlay
    short* vBl  = (short*)smem;
    float* red  = (float*)(smem + 36864);

    int blk = blockIdx.x, n = blk >> 3, g = blk & 7, tid = threadIdx.x;
    size_t sb = ((size_t)g * 50176 + (size_t)n * 56) * 64;
    short* svdst = qkP + sb;
    short* vHs   = vP + sb;

    float a0 = asim[g], a1 = asim[8 + g], a2 = asim[16 + g];
    float bb = bsim[g] + bsim[8 + g] + bsim[16 + g];

    // T14: issue vH global load early (held in regs until vBl write)
    bf16x8 vreg = {0, 0, 0, 0, 0, 0, 0, 0};
    int vc = tid / 7, vch = tid - vc * 7;       // valid for tid < 448
    if (tid < 448)
        vreg = *reinterpret_cast<const bf16x8*>(vHs + vc * 56 + vch * 8);

    // stage q/k rows with inline BN affine -> qkTl[part][i][40]
    for (int u = tid; u < 448; u += 512) {
        int i = u >> 3, c0 = (u & 7) << 3;
        bf16x8 raw = *reinterpret_cast<const bf16x8*>(svdst + i * 64 + c0);
        bf16x8 t;
#pragma unroll
        for (int uu = 0; uu < 8; ++uu) {
            int o = g * 128 + c0 + uu;
            t[uu] = f2bfbits(aq[o] * bfbits2f(raw[uu]) + bq[o]);
        }
        *reinterpret_cast<bf16x8*>(&qkTl[((c0 & 32) ? 2560 : 0) + i * 40 + (c0 & 31)]) = t;
    }
    for (int u = tid; u < 640; u += 512) {
        int part = u / 320, r = u - part * 320;
        qkTl[part * 2560 + (56 + r / 40) * 40 + (r % 40)] = 0;
    }
    for (int e = tid; e < 3192; e += 512) qkl[e] = bb;
    __syncthreads();

    int w = tid >> 6, l = tid & 63, m = w >> 1, s = w & 1, la = l & 15, lb = l >> 4;
    int i0 = m * 16 + lb * 4;
    bf16x8 aqf = *reinterpret_cast<const bf16x8*>(&qkTl[(m * 16 + la) * 40 + lb * 8]);
    bf16x8 akf = *reinterpret_cast<const bf16x8*>(&qkTl[(64 + m * 16 + la) * 40 + lb * 8]);
    int ndt = s ? 3 : 4, dt0 = s * 4;

    // term 1: qk (each (i,j) cell written by exactly one lane)
    __builtin_amdgcn_s_setprio(1);
#pragma unroll
    for (int t = 0; t < 2; ++t) {
        int nt = 2 * s + t;
        bf16x8 bk = *reinterpret_cast<const bf16x8*>(&qkTl[(64 + nt * 16 + la) * 40 + lb * 8]);
        f32x4 acc = {0, 0, 0, 0};
        acc = MFMA16(aqf, bk, acc);
        int j = nt * 16 + la;
        if (j < 56) {
#pragma unroll
            for (int r = 0; r < 4; ++r) {
                int i = i0 + r;
                if (i < 56) qkl[i * 57 + j] += a0 * acc[r];
            }
        }
    }
    __builtin_amdgcn_s_setprio(0);
    __syncthreads();

    // term 2: Sq -> qkl[i][i-d+55]
    __builtin_amdgcn_s_setprio(1);
    for (int t = 0; t < ndt; ++t) {
        int dt = dt0 + t;
        bf16x8 br = *reinterpret_cast<const bf16x8*>(relTq + (dt * 16 + la) * 32 + lb * 8);
        f32x4 acc = {0, 0, 0, 0};
        acc = MFMA16(aqf, br, acc);
        int d = dt * 16 + la;
#pragma unroll
        for (int r = 0; r < 4; ++r) {
            int i = i0 + r;
            int j = i - d + 55;
            if (i < 56 && j >= 0 && j < 56) qkl[i * 57 + j] += a1 * acc[r];
        }
    }
    __builtin_amdgcn_s_setprio(0);
    __syncthreads();

    // term 3: Kr -> qkl[jj-d+55][jj]
    __builtin_amdgcn_s_setprio(1);
    for (int t = 0; t < ndt; ++t) {
        int dt = dt0 + t;
        bf16x8 br = *reinterpret_cast<const bf16x8*>(relTk + (dt * 16 + la) * 32 + lb * 8);
        f32x4 acc = {0, 0, 0, 0};
        acc = MFMA16(akf, br, acc);
        int d = dt * 16 + la;
#pragma unroll
        for (int r = 0; r < 4; ++r) {
            int jj = i0 + r;
            int i = jj - d + 55;
            if (jj < 56 && i >= 0 && i < 56) qkl[i * 57 + jj] += a2 * acc[r];
        }
    }
    __builtin_amdgcn_s_setprio(0);
    __syncthreads();

    // write pre-loaded vH regs into vBl (qkTl dead); zero pad cols 56..71
    if (tid < 448)
        *reinterpret_cast<bf16x8*>(&vBl[vc * 72 + vch * 8]) = vreg;
    if (tid < 128) {
        int c = tid >> 1, chp = tid & 1;
        bf16x8 z = {0, 0, 0, 0, 0, 0, 0, 0};
        *reinterpret_cast<bf16x8*>(&vBl[c * 72 + 56 + chp * 8]) = z;
    }
    // softmax: no-max (BN-bounded scores), rcp divide
    float p[7];
#pragma unroll
    for (int rr = 0; rr < 7; ++rr) {
        int i = w * 7 + rr;
        float e = (l < 56) ? __expf(qkl[i * 57 + l]) : 0.f;
        float su = e;
#pragma unroll
        for (int off = 32; off; off >>= 1) su += __shfl_xor(su, off);
        p[rr] = e * __builtin_amdgcn_rcpf(su);
    }
    __syncthreads();   // qkl reads done (simB/Pb overlay it)

#pragma unroll
    for (int rr = 0; rr < 7; ++rr) {
        int i = w * 7 + rr;
        short pv = f2bfbits(p[rr]);
        simB[i * 72 + l] = (l < 56) ? pv : (short)0;
        if (l < 56) Pb[i * 136 + (i - l + 55)] = pv;
        if (l < i || l > i + 55) Pb[i * 136 + l] = 0;
        if (l > i - 9) Pb[i * 136 + l + 64] = 0;
        if (l < 8) Pb[i * 136 + l + 128] = 0;
    }
    __syncthreads();

    // phase 2: sv = v . P^T ; sve = rel_v . Pskew^T
    f32x4 sva[2]  = {{0, 0, 0, 0}, {0, 0, 0, 0}};
    f32x4 svea[2] = {{0, 0, 0, 0}, {0, 0, 0, 0}};
    __builtin_amdgcn_s_setprio(1);
#pragma unroll
    for (int ks = 0; ks < 2; ++ks) {
        bf16x8 av = *reinterpret_cast<const bf16x8*>(&vBl[(m * 16 + la) * 72 + ks * 32 + lb * 8]);
#pragma unroll
        for (int t = 0; t < 2; ++t) {
            int nt = 2 * s + t;
            bf16x8 bsf = *reinterpret_cast<const bf16x8*>(&simB[(nt * 16 + la) * 72 + ks * 32 + lb * 8]);
            sva[t] = MFMA16(av, bsf, sva[t]);
        }
    }
#pragma unroll
    for (int ks = 0; ks < 4; ++ks) {
        bf16x8 ar = *reinterpret_cast<const bf16x8*>(relBv + (m * 16 + la) * 128 + ks * 32 + lb * 8);
#pragma unroll
        for (int t = 0; t < 2; ++t) {
            int nt = 2 * s + t;
            bf16x8 bp = *reinterpret_cast<const bf16x8*>(&Pb[(nt * 16 + la) * 136 + ks * 32 + lb * 8]);
            svea[t] = MFMA16(ar, bp, svea[t]);
        }
    }
    __builtin_amdgcn_s_setprio(0);
    // store sv -> qkP slice, sve -> vP slice + out-BN partial stats
    float st0[4] = {0, 0, 0, 0}, st1[4] = {0, 0, 0, 0}, st2[4] = {0, 0, 0, 0}, st3[4] = {0, 0, 0, 0};
#pragma unroll
    for (int t = 0; t < 2; ++t) {
        int i = (2 * s + t) * 16 + la;
        bool ok = i < 56;
#pragma unroll
        for (int r = 0; r < 4; ++r) {
            int c = m * 16 + lb * 4 + r;
            float va = sva[t][r], ve = svea[t][r];
            if (ok) {
                svdst[c * 56 + i] = f2bfbits(va);
                vHs  [c * 56 + i] = f2bfbits(ve);
                st0[r] += va; st1[r] += va * va; st2[r] += ve; st3[r] += ve * ve;
            }
        }
    }
#pragma unroll
    for (int r = 0; r < 4; ++r) {
#pragma unroll
        for (int mk = 1; mk < 16; mk <<= 1) {
            st0[r] += __shfl_xor(st0[r], mk);
            st1[r] += __shfl_xor(st1[r], mk);
            st2[r] += __shfl_xor(st2[r], mk);
            st3[r] += __shfl_xor(st3[r], mk);
        }
    }
    if (la == 0) {
#pragma unroll
        for (int r = 0; r < 4; ++r) {
            int c = m * 16 + lb * 4 + r;
            red[(0 * 64 + c) * 2 + s] = st0[r];
            red[(1 * 64 + c) * 2 + s] = st1[r];
            red[(2 * 64 + c) * 2 + s] = st2[r];
            red[(3 * 64 + c) * 2 + s] = st3[r];
        }
    }
    __syncthreads();
    if (tid < 64) {
        int c = tid, o2 = (g * 64 + c) * 2, bkt = blk & 7;
        atomicAdd(&osum[o2 * 8 + bkt],       red[(0 * 64 + c) * 2] + red[(0 * 64 + c) * 2 + 1]);
        atomicAdd(&osq [o2 * 8 + bkt],       red[(1 * 64 + c) * 2] + red[(1 * 64 + c) * 2 + 1]);
        atomicAdd(&osum[(o2 + 1) * 8 + bkt], red[(2 * 64 + c) * 2] + red[(2 * 64 + c) * 2 + 1]);
        atomicAdd(&osq [(o2 + 1) * 8 + bkt], red[(3 * 64 + c) * 2] + red[(3 * 64 + c) * 2 + 1]);
    }
}

__global__ __launch_bounds__(256) void k3b_coef(const float* __restrict__ osum, const float* __restrict__ osq,
                                                const float* __restrict__ go, const float* __restrict__ bo,
                                                float* __restrict__ a_c, float* __restrict__ b_c) {
    int o = blockIdx.x * 256 + threadIdx.x;
    float s = 0, s2 = 0;
#pragma unroll
    for (int k = 0; k < 8; ++k) { s += osum[o * 8 + k]; s2 += osq[o * 8 + k]; }
    float inv = 1.f / 50176.f;
    float mean = s * inv;
    float var = s2 * inv - mean * mean;
    float a = go[o] * rsqrtf(var + EPS);
    a_c[o] = a; b_c[o] = bo[o] - a * mean;
}

// ---------------- K4 ----------------
__global__ __launch_bounds__(256) void k4_out(const short* __restrict__ svq,
                                              const short* __restrict__ sve,
                                              const float* __restrict__ ao, const float* __restrict__ bo,
                                              float* __restrict__ out) {
    int blk = blockIdx.x;
    int oc = blk & 511, bt = blk >> 9;
    int b = bt >> 2, tt = bt & 3;
    int g = oc >> 6, c = oc & 63;
    __shared__ float tile[56][57];
    int tid = threadIdx.x;
    int o_sv = oc * 2, o_sve = oc * 2 + 1;
    float asv = ao[o_sv], bsv = bo[o_sv], asve = ao[o_sve], bsve = bo[o_sve];
    float badd = bsv + bsve;
    int nbase = (b * 4 + tt) * 56;
    for (int e = tid; e < 3136; e += 256) {
        int wq = e / 56, h = e - wq * 56;
        size_t idx = ((size_t)g * 50176 + (size_t)(nbase + wq) * 56) * 64 + c * 56 + h;
        tile[wq][h] = asv * bfbits2f(svq[idx]) + asve * bfbits2f(sve[idx]) + badd;
    }
    __syncthreads();
    size_t ob = ((size_t)(b * 512 + oc) * 4 + tt) * 3136;
    for (int e = tid; e < 3136; e += 256) {
        int h = e / 56, wq = e - h * 56;
        out[ob + h * 56 + wq] = tile[wq][h];
    }
}

extern "C" void kernel_launch(void* const* d_in, const int* in_sizes, int n_in,
                              void* d_out, int out_size, void* d_ws, size_t ws_size,
                              hipStream_t stream) {
    (void)in_sizes; (void)n_in; (void)out_size; (void)ws_size;
    const float* x     = (const float*)d_in[0];
    const float* w_qkv = (const float*)d_in[1];
    const float* g_qkv = (const float*)d_in[2];
    const float* b_qkv = (const float*)d_in[3];
    const float* rel   = (const float*)d_in[4];
    const float* g_sim = (const float*)d_in[5];
    const float* b_sim = (const float*)d_in[6];
    const float* g_out = (const float*)d_in[7];
    const float* b_out = (const float*)d_in[8];
    float* ws  = (float*)d_ws;
    float* out = (float*)d_out;
    short* qkP = (short*)((char*)d_ws + 131072);
    short* vP  = (short*)((char*)d_ws + 51511296);
    bf*    xbt = (bf*)d_out;
    bf*    wb  = (bf*)((char*)d_out + 51380224);
    short* relTq = (short*)((char*)d_out + 73400320);
    short* relTk = relTq + 3584;
    short* relBv = relTk + 3584;

    hipMemsetAsync(ws, 0, WS_ZERO_END * sizeof(float), stream);
    k0_transpose<<<896, 256, 0, stream>>>(x, xbt);
    kw_conv<<<512, 256, 0, stream>>>(w_qkv, wb);
    kprep<<<46, 256, 0, stream>>>(rel, relTq, relTk, relBv);
    k1_mfma<<<dim3(8, 448), 256, 0, stream>>>(xbt, wb, qkP, vP, ws + WS_QSUM, ws + WS_QSQ);
    k1b_coef<<<4, 256, 0, stream>>>(ws + WS_QSUM, ws + WS_QSQ, g_qkv, b_qkv,
                                    ws + WS_AQKV, ws + WS_BQKV);
    kbn2<<<7168, 512, 0, stream>>>(qkP, vP, ws + WS_AQKV, ws + WS_BQKV,
                                   relTq, relTk, ws + WS_SIMSUM, ws + WS_SIMSQ);
    k2b_coef<<<1, 64, 0, stream>>>(ws + WS_SIMSUM, ws + WS_SIMSQ, g_sim, b_sim,
                                   ws + WS_ASIM, ws + WS_BSIM);
    k3_mfma<<<7168, 512, 0, stream>>>(relTq, relTk, relBv, qkP, vP,
                                      ws + WS_AQKV, ws + WS_BQKV,
                                      ws + WS_ASIM, ws + WS_BSIM,
                                      ws + WS_OUTSUM, ws + WS_OUTSQ);
    k3b_coef<<<4, 256, 0, stream>>>(ws + WS_OUTSUM, ws + WS_OUTSQ, g_out, b_out,
                                    ws + WS_AOUT, ws + WS_BOUT);
    k4_out<<<8192, 256, 0, stream>>>(qkP, vP, ws + WS_AOUT, ws + WS_BOUT, out);
}

// Round 15
// 426.774 us; speedup vs baseline: 1.7608x; 1.0343x over previous
//
#include <hip/hip_runtime.h>
#include <hip/hip_bf16.h>

#define EPS 1e-5f
typedef __hip_bfloat16 bf;
typedef __attribute__((ext_vector_type(8))) short bf16x8;
typedef __attribute__((ext_vector_type(4))) short s16x4;
typedef __attribute__((ext_vector_type(4))) float f32x4;

#define MFMA16(a, b, c) __builtin_amdgcn_mfma_f32_16x16x32_bf16(a, b, c, 0, 0, 0)

// Sizes: B=4, C_IN=512, T=4, H=W=K=56, G=8, GP=64, OCH=1024 ; NB=896 ; NP=50176
#define WS_QSUM     0
#define WS_QSQ      4096
#define WS_SIMSUM   8192
#define WS_SIMSQ    9728
#define WS_OUTSUM   11264
#define WS_OUTSQ    19456
#define WS_ZERO_END 27648
#define WS_AQKV     27648
#define WS_BQKV     28672
#define WS_ASIM     29696
#define WS_BSIM     29728
#define WS_AOUT     29760
#define WS_BOUT     30784
// ws bytes: qkP [8][50176][64] bf16 @131072; vP same @51,511,296. total 102.89MB
// d_out scratch: xbt bf16 [50176][512] @0 ; wb @51,380,224 ; rel tables @73,400,320.

__device__ __forceinline__ void gload_lds16(const void* g, void* l) {
    __builtin_amdgcn_global_load_lds(
        (const __attribute__((address_space(1))) void*)g,
        (__attribute__((address_space(3))) void*)l, 16, 0, 0);
}
__device__ __forceinline__ float bfbits2f(short b) {
    return __uint_as_float(((uint32_t)(unsigned short)b) << 16);
}
__device__ __forceinline__ short f2bfbits(float f) {
    return (short)__hip_bfloat16_raw(__float2bfloat16(f)).x;
}

// ---------------- K0 ----------------
__global__ __launch_bounds__(256) void k0_transpose(const float* __restrict__ x,
                                                    bf* __restrict__ xbt) {
    int bid = blockIdx.x;
    int h = bid % 56, bt = bid / 56;
    int b = bt >> 2, t = bt & 3;
    __shared__ short tile[512 * 57];
    const float* src = x + (((size_t)(b * 512) * 4 + t) * 3136) + h * 56;
    for (int e = threadIdx.x; e < 512 * 56; e += 256) {
        int c = e / 56, w = e - c * 56;
        tile[c * 57 + w] = f2bfbits(src[(size_t)c * 12544 + w]);
    }
    __syncthreads();
    short* dst = reinterpret_cast<short*>(xbt);
    size_t pbase = ((size_t)bt * 56) * 56 + h;
    for (int e = threadIdx.x; e < 512 * 56; e += 256) {
        int w = e >> 9, c = e & 511;
        dst[(pbase + (size_t)w * 56) * 512 + c] = tile[c * 57 + w];
    }
}

// ---------------- KW ----------------
__global__ __launch_bounds__(256) void kw_conv(const float* __restrict__ w, bf* __restrict__ wb) {
    int i = (blockIdx.x * 256 + threadIdx.x) * 4;
#pragma unroll
    for (int u = 0; u < 4; ++u) wb[i + u] = __float2bfloat16(w[i + u]);
}

// ---------------- KPREP ----------------
__global__ __launch_bounds__(256) void kprep(const float* __restrict__ rel,
                                             short* __restrict__ relTq,
                                             short* __restrict__ relTk,
                                             short* __restrict__ relBv) {
    int tid = blockIdx.x * 256 + threadIdx.x;
    if (tid < 3584) {
        int d = tid >> 5, c = tid & 31;
        relTq[tid] = f2bfbits(d < 111 ? rel[c * 111 + d] : 0.f);
        relTk[tid] = f2bfbits(d < 111 ? rel[(32 + c) * 111 + d] : 0.f);
    } else if (tid < 11776) {
        int u = tid - 3584, c = u >> 7, d = u & 127;
        relBv[u] = f2bfbits(d < 111 ? rel[(64 + c) * 111 + d] : 0.f);
    }
}

// ---------------- K1: single-buffer 30KB MFMA GEMM + XOR swizzle, g-fastest grid ----------------
__global__ __launch_bounds__(256) void k1_mfma(const bf* __restrict__ xbt,
                                               const bf* __restrict__ wb,
                                               short* __restrict__ qkP,
                                               short* __restrict__ vP,
                                               float* __restrict__ qsum,
                                               float* __restrict__ qsq) {
    __shared__ __align__(16) short As[8192];
    __shared__ __align__(16) short Bs[7168];
    int tid = threadIdx.x;
    int g  = blockIdx.x;
    int p0 = blockIdx.y * 112;
    int o0 = g * 128;
    const short* aG = reinterpret_cast<const short*>(wb);
    const short* bG = reinterpret_cast<const short*>(xbt);
    int wv = tid >> 6, l = tid & 63, r16 = l & 15, q4 = l >> 4;

    f32x4 acc[2][7];
#pragma unroll
    for (int i = 0; i < 2; ++i)
#pragma unroll
        for (int j = 0; j < 7; ++j) acc[i][j] = (f32x4){0.f, 0.f, 0.f, 0.f};

    int rowa0 = wv * 32 + r16, rowa1 = rowa0 + 16;

    for (int k0 = 0; k0 < 512; k0 += 64) {
        int ch = tid;
#pragma unroll
        for (int it = 0; it < 4; ++it, ch += 256) {
            int row = ch >> 3, c = ch & 7;
            int gc = (c ^ row) & 7;
            gload_lds16(aG + (((size_t)(o0 + row)) << 9) + k0 + gc * 8, &As[ch << 3]);
        }
        ch = tid;
#pragma unroll
        for (int it = 0; it < 3; ++it, ch += 256) {
            int row = ch >> 3, c = ch & 7;
            int gc = (c ^ row) & 7;
            gload_lds16(bG + (((size_t)(p0 + row)) << 9) + k0 + gc * 8, &Bs[ch << 3]);
        }
        if (tid < 128) {
            int u = tid + 768;
            int row = u >> 3, c = u & 7;
            int gc = (c ^ row) & 7;
            gload_lds16(bG + (((size_t)(p0 + row)) << 9) + k0 + gc * 8, &Bs[u << 3]);
        }
        __syncthreads();
#pragma unroll
        for (int kk = 0; kk < 2; ++kk) {
            int wch = kk * 4 + q4;
            bf16x8 a0 = *reinterpret_cast<const bf16x8*>(&As[rowa0 * 64 + ((wch ^ rowa0) & 7) * 8]);
            bf16x8 a1 = *reinterpret_cast<const bf16x8*>(&As[rowa1 * 64 + ((wch ^ rowa1) & 7) * 8]);
#pragma unroll
            for (int j = 0; j < 7; ++j) {
                int rowb = j * 16 + r16;
                bf16x8 bj = *reinterpret_cast<const bf16x8*>(&Bs[rowb * 64 + ((wch ^ rowb) & 7) * 8]);
                acc[0][j] = MFMA16(a0, bj, acc[0][j]);
                acc[1][j] = MFMA16(a1, bj, acc[1][j]);
            }
        }
        __syncthreads();
    }
    int bkt = blockIdx.y & 3;
#pragma unroll
    for (int i = 0; i < 2; ++i)
#pragma unroll
        for (int r = 0; r < 4; ++r) {
            float sA = 0.f, sB = 0.f;
#pragma unroll
            for (int j = 0; j < 7; ++j) { float v = acc[i][j][r]; sA += v; sB += v * v; }
#pragma unroll
            for (int mk = 1; mk < 16; mk <<= 1) { sA += __shfl_xor(sA, mk); sB += __shfl_xor(sB, mk); }
            if (r16 == 0) {
                int o = o0 + wv * 32 + i * 16 + q4 * 4 + r;
                atomicAdd(&qsum[o * 4 + bkt], sA);
                atomicAdd(&qsq [o * 4 + bkt], sB);
            }
        }
#pragma unroll
    for (int j = 0; j < 7; ++j) {
        int p = p0 + j * 16 + r16;
        size_t rowb = ((size_t)g * 50176 + p) * 64;
#pragma unroll
        for (int i = 0; i < 2; ++i) {
            int op = wv * 32 + i * 16 + q4 * 4;
            s16x4 pk;
#pragma unroll
            for (int r = 0; r < 4; ++r) pk[r] = f2bfbits(acc[i][j][r]);
            short* dst = (op < 64) ? (qkP + rowb + op) : (vP + rowb + (op - 64));
            *reinterpret_cast<s16x4*>(dst) = pk;
        }
    }
}

// ---------------- K1b ----------------
__global__ __launch_bounds__(256) void k1b_coef(const float* __restrict__ qsum, const float* __restrict__ qsq,
                                                const float* __restrict__ gamma, const float* __restrict__ beta,
                                                float* __restrict__ a_c, float* __restrict__ b_c) {
    int o = blockIdx.x * 256 + threadIdx.x;
    float s = qsum[o * 4] + qsum[o * 4 + 1] + qsum[o * 4 + 2] + qsum[o * 4 + 3];
    float s2 = qsq[o * 4] + qsq[o * 4 + 1] + qsq[o * 4 + 2] + qsq[o * 4 + 3];
    float inv = 1.f / 50176.f;
    float mean = s * inv;
    float var = s2 * inv - mean * mean;
    float a = gamma[o] * rsqrtf(var + EPS);
    a_c[o] = a; b_c[o] = beta[o] - a * mean;
}

// ---------------- KBN2: affine q/k (write-back in-place) + v -> vH (in-place) + sim BN stats ----------------
__global__ __launch_bounds__(512) void kbn2(short* __restrict__ qkP,
                                            short* __restrict__ vP,
                                            const float* __restrict__ aq, const float* __restrict__ bq,
                                            const short* __restrict__ relTq,
                                            const short* __restrict__ relTk,
                                            float* __restrict__ ssum, float* __restrict__ ssq) {
    __shared__ __align__(16) short qkTl[5120];
    __shared__ short vtl[64 * 57];
    __shared__ float red[48];
    int blk = blockIdx.x, n = blk >> 3, g = blk & 7, tid = threadIdx.x;
    size_t sb = ((size_t)g * 50176 + (size_t)n * 56) * 64;
    short* qsrc = qkP + sb;
    short* vsrc = vP + sb;
    // q/k rows: affine, write back in-place (k3 re-reads the rounded values), stage to qkTl
    for (int u = tid; u < 448; u += 512) {
        int i = u >> 3, c0 = (u & 7) << 3;
        bf16x8 raw = *reinterpret_cast<const bf16x8*>(qsrc + i * 64 + c0);
        bf16x8 t;
#pragma unroll
        for (int uu = 0; uu < 8; ++uu) {
            int o = g * 128 + c0 + uu;
            t[uu] = f2bfbits(aq[o] * bfbits2f(raw[uu]) + bq[o]);
        }
        *reinterpret_cast<bf16x8*>(qsrc + i * 64 + c0) = t;
        *reinterpret_cast<bf16x8*>(&qkTl[((c0 & 32) ? 2560 : 0) + i * 40 + (c0 & 31)]) = t;
    }
    for (int u = tid; u < 640; u += 512) {
        int part = u / 320, r = u - part * 320;
        qkTl[part * 2560 + (56 + r / 40) * 40 + (r % 40)] = 0;
    }
    for (int u = tid; u < 448; u += 512) {
        int i = u >> 3, c0 = (u & 7) << 3;
        bf16x8 raw = *reinterpret_cast<const bf16x8*>(vsrc + i * 64 + c0);
#pragma unroll
        for (int uu = 0; uu < 8; ++uu) {
            int o = g * 128 + 64 + c0 + uu;
            vtl[(c0 + uu) * 57 + i] = f2bfbits(aq[o] * bfbits2f(raw[uu]) + bq[o]);
        }
    }
    __syncthreads();
    for (int u = tid; u < 448; u += 512) {
        int c = u / 7, h0 = (u - c * 7) * 8;
        bf16x8 t;
#pragma unroll
        for (int uu = 0; uu < 8; ++uu) t[uu] = vtl[c * 57 + h0 + uu];
        *reinterpret_cast<bf16x8*>(vsrc + c * 56 + h0) = t;
    }
    int w = tid >> 6, l = tid & 63, m = w >> 1, s = w & 1, la = l & 15, lb = l >> 4;
    bf16x8 aqf = *reinterpret_cast<const bf16x8*>(&qkTl[(m * 16 + la) * 40 + lb * 8]);
    bf16x8 akf = *reinterpret_cast<const bf16x8*>(&qkTl[2560 + (m * 16 + la) * 40 + lb * 8]);
    float s0 = 0, s1 = 0, s2v = 0, q0 = 0, q1 = 0, q2 = 0;
#pragma unroll
    for (int t = 0; t < 2; ++t) {
        int nt = 2 * s + t;
        bf16x8 bk = *reinterpret_cast<const bf16x8*>(&qkTl[2560 + (nt * 16 + la) * 40 + lb * 8]);
        f32x4 acc = {0, 0, 0, 0};
        acc = MFMA16(aqf, bk, acc);
        int j = nt * 16 + la;
        if (j < 56) {
#pragma unroll
            for (int r = 0; r < 4; ++r) {
                int i = m * 16 + lb * 4 + r;
                if (i < 56) { float v = acc[r]; s0 += v; q0 += v * v; }
            }
        }
    }
    int ndt = s ? 3 : 4, dt0 = s * 4;
    for (int t = 0; t < ndt; ++t) {
        int dt = dt0 + t;
        bf16x8 br = *reinterpret_cast<const bf16x8*>(relTq + (dt * 16 + la) * 32 + lb * 8);
        f32x4 acc = {0, 0, 0, 0};
        acc = MFMA16(aqf, br, acc);
        int d = dt * 16 + la;
#pragma unroll
        for (int r = 0; r < 4; ++r) {
            int i = m * 16 + lb * 4 + r;
            if (i < 56 && d >= i && d <= i + 55) { float v = acc[r]; s1 += v; q1 += v * v; }
        }
    }
    for (int t = 0; t < ndt; ++t) {
        int dt = dt0 + t;
        bf16x8 br = *reinterpret_cast<const bf16x8*>(relTk + (dt * 16 + la) * 32 + lb * 8);
        f32x4 acc = {0, 0, 0, 0};
        acc = MFMA16(akf, br, acc);
        int d = dt * 16 + la;
#pragma unroll
        for (int r = 0; r < 4; ++r) {
            int j = m * 16 + lb * 4 + r;
            if (j < 56 && d >= j && d <= j + 55) { float v = acc[r]; s2v += v; q2 += v * v; }
        }
    }
    float vals[6] = {s0, s1, s2v, q0, q1, q2};
#pragma unroll
    for (int v = 0; v < 6; ++v) {
        for (int off = 32; off; off >>= 1) vals[v] += __shfl_down(vals[v], off);
        if (l == 0) red[v * 8 + w] = vals[v];
    }
    __syncthreads();
    if (tid < 6) {
        float tot = 0;
#pragma unroll
        for (int k = 0; k < 8; ++k) tot += red[tid * 8 + k];
        int comp = (tid < 3) ? tid : tid - 3;
        int ch = comp * 8 + g;
        int bkt = blk & 63;
        atomicAdd((tid < 3 ? ssum : ssq) + ch * 64 + bkt, tot);
    }
}

__global__ void k2b_coef(const float* __restrict__ ssum, const float* __restrict__ ssq,
                         const float* __restrict__ gs, const float* __restrict__ bs,
                         float* __restrict__ a_c, float* __restrict__ b_c) {
    int c = threadIdx.x;
    if (c >= 24) return;
    float s = 0, s2 = 0;
    for (int k = 0; k < 64; ++k) { s += ssum[c * 64 + k]; s2 += ssq[c * 64 + k]; }
    float inv = 1.f / 2809856.f;
    float mean = s * inv;
    float var = s2 * inv - mean * mean;
    float a = gs[c] * rsqrtf(var + EPS);
    a_c[c] = a; b_c[c] = bs[c] - a * mean;
}

// ---------------- K3: attention core — store/RMW/store score assembly, pre-affined q/k ----------------
// LDS (38912 B): qkTl@0 [2][64][40] (10240; dead after term1 -> KrB [56][57] bf16 (6384) overlays;
//   phase2 vBl [64][72] overlays) | qkl@10240 [56][57] f32 (12768; phase2 simB overlays)
//   | Pb@19456 [64][136] (ends 36864) | red@36864 (2048) -> 38912 total, 4 blocks/CU.
// term1 (qk): plain store bb+a0*acc (covers all read cells -> no init). term2 (Sq): += into qkl.
// term3 (Kr): plain bf16 store into KrB (same phase as term2, different buffer). Softmax: qkl+KrB,
// no-max (BN-bounded), rcp. vBl written after softmax barrier (KrB region dead then).
__global__ __launch_bounds__(512) void k3_mfma(const short* __restrict__ relTq,
                                               const short* __restrict__ relTk,
                                               const short* __restrict__ relBv,
                                               short* __restrict__ qkP,   // affined q/k in, sv out
                                               short* __restrict__ vP,    // vH in, sve out
                                               const float* __restrict__ asim, const float* __restrict__ bsim,
                                               float* __restrict__ osum, float* __restrict__ osq) {
    __shared__ __align__(16) char smem[38912];
    short* qkTl = (short*)smem;                 // [2][64][40]
    short* KrB  = (short*)smem;                 // [56][57] bf16, overlays qkTl after term1
    float* qkl  = (float*)(smem + 10240);       // [56][57] f32
    short* simB = (short*)(smem + 10240);       // phase2 overlay
    short* Pb   = (short*)(smem + 19456);       // phase2 overlay
    short* vBl  = (short*)smem;                 // phase2 overlay
    float* red  = (float*)(smem + 36864);

    int blk = blockIdx.x, n = blk >> 3, g = blk & 7, tid = threadIdx.x;
    size_t sb = ((size_t)g * 50176 + (size_t)n * 56) * 64;
    short* svdst = qkP + sb;
    short* vHs   = vP + sb;

    float a0 = asim[g], a1 = asim[8 + g], a2 = asim[16 + g];
    float bb = bsim[g] + bsim[8 + g] + bsim[16 + g];

    // T14: issue vH global load early (held in regs until after softmax)
    bf16x8 vreg = {0, 0, 0, 0, 0, 0, 0, 0};
    int vc = tid / 7, vch = tid - vc * 7;
    if (tid < 448)
        vreg = *reinterpret_cast<const bf16x8*>(vHs + vc * 56 + vch * 8);

    // stage pre-affined q/k rows (pure copy) -> qkTl[part][i][40]
    for (int u = tid; u < 448; u += 512) {
        int i = u >> 3, c0 = (u & 7) << 3;
        bf16x8 t = *reinterpret_cast<const bf16x8*>(svdst + i * 64 + c0);
        *reinterpret_cast<bf16x8*>(&qkTl[((c0 & 32) ? 2560 : 0) + i * 40 + (c0 & 31)]) = t;
    }
    for (int u = tid; u < 640; u += 512) {
        int part = u / 320, r = u - part * 320;
        qkTl[part * 2560 + (56 + r / 40) * 40 + (r % 40)] = 0;
    }
    __syncthreads();

    int w = tid >> 6, l = tid & 63, m = w >> 1, s = w & 1, la = l & 15, lb = l >> 4;
    int i0 = m * 16 + lb * 4;
    bf16x8 aqf = *reinterpret_cast<const bf16x8*>(&qkTl[(m * 16 + la) * 40 + lb * 8]);
    bf16x8 akf = *reinterpret_cast<const bf16x8*>(&qkTl[(64 + m * 16 + la) * 40 + lb * 8]);
    int ndt = s ? 3 : 4, dt0 = s * 4;

    // term 1: qk -> plain store (each read cell written exactly once; pads never read)
    __builtin_amdgcn_s_setprio(1);
#pragma unroll
    for (int t = 0; t < 2; ++t) {
        int nt = 2 * s + t;
        bf16x8 bk = *reinterpret_cast<const bf16x8*>(&qkTl[(64 + nt * 16 + la) * 40 + lb * 8]);
        f32x4 acc = {0, 0, 0, 0};
        acc = MFMA16(aqf, bk, acc);
        int j = nt * 16 + la;
        if (j < 56) {
#pragma unroll
            for (int r = 0; r < 4; ++r) {
                int i = i0 + r;
                if (i < 56) qkl[i * 57 + j] = bb + a0 * acc[r];
            }
        }
    }
    __builtin_amdgcn_s_setprio(0);
    __syncthreads();   // term1 stores + all qkTl MFMA reads complete

    // term 2: Sq += into qkl ; term 3: Kr -> KrB plain store (overlays dead qkTl)
    __builtin_amdgcn_s_setprio(1);
    for (int t = 0; t < ndt; ++t) {
        int dt = dt0 + t;
        bf16x8 br = *reinterpret_cast<const bf16x8*>(relTq + (dt * 16 + la) * 32 + lb * 8);
        f32x4 acc = {0, 0, 0, 0};
        acc = MFMA16(aqf, br, acc);
        int d = dt * 16 + la;
#pragma unroll
        for (int r = 0; r < 4; ++r) {
            int i = i0 + r;
            int j = i - d + 55;
            if (i < 56 && j >= 0 && j < 56) qkl[i * 57 + j] += a1 * acc[r];
        }
    }
    for (int t = 0; t < ndt; ++t) {
        int dt = dt0 + t;
        bf16x8 br = *reinterpret_cast<const bf16x8*>(relTk + (dt * 16 + la) * 32 + lb * 8);
        f32x4 acc = {0, 0, 0, 0};
        acc = MFMA16(akf, br, acc);
        int d = dt * 16 + la;
#pragma unroll
        for (int r = 0; r < 4; ++r) {
            int jj = i0 + r;
            int i = jj - d + 55;
            if (jj < 56 && i >= 0 && i < 56) KrB[i * 57 + jj] = f2bfbits(a2 * acc[r]);
        }
    }
    __builtin_amdgcn_s_setprio(0);
    __syncthreads();

    // softmax: sc = qkl + KrB ; no-max, rcp divide
    float p[7];
#pragma unroll
    for (int rr = 0; rr < 7; ++rr) {
        int i = w * 7 + rr;
        float e = 0.f;
        if (l < 56)
            e = __expf(qkl[i * 57 + l] + bfbits2f(KrB[i * 57 + l]));
        float su = e;
#pragma unroll
        for (int off = 32; off; off >>= 1) su += __shfl_xor(su, off);
        p[rr] = e * __builtin_amdgcn_rcpf(su);
    }
    __syncthreads();   // qkl + KrB reads done (vBl/simB/Pb overlay them)

    // vBl write (T14 regs land here), zero pad cols; simB/Pb builds
    if (tid < 448)
        *reinterpret_cast<bf16x8*>(&vBl[vc * 72 + vch * 8]) = vreg;
    if (tid < 128) {
        int c = tid >> 1, chp = tid & 1;
        bf16x8 z = {0, 0, 0, 0, 0, 0, 0, 0};
        *reinterpret_cast<bf16x8*>(&vBl[c * 72 + 56 + chp * 8]) = z;
    }
#pragma unroll
    for (int rr = 0; rr < 7; ++rr) {
        int i = w * 7 + rr;
        short pv = f2bfbits(p[rr]);
        simB[i * 72 + l] = (l < 56) ? pv : (short)0;
        if (l < 56) Pb[i * 136 + (i - l + 55)] = pv;
        if (l < i || l > i + 55) Pb[i * 136 + l] = 0;
        if (l > i - 9) Pb[i * 136 + l + 64] = 0;
        if (l < 8) Pb[i * 136 + l + 128] = 0;
    }
    __syncthreads();

    // phase 2: sv = v . P^T ; sve = rel_v . Pskew^T
    f32x4 sva[2]  = {{0, 0, 0, 0}, {0, 0, 0, 0}};
    f32x4 svea[2] = {{0, 0, 0, 0}, {0, 0, 0, 0}};
    __builtin_amdgcn_s_setprio(1);
#pragma unroll
    for (int ks = 0; ks < 2; ++ks) {
        bf16x8 av = *reinterpret_cast<const bf16x8*>(&vBl[(m * 16 + la) * 72 + ks * 32 + lb * 8]);
#pragma unroll
        for (int t = 0; t < 2; ++t) {
            int nt = 2 * s + t;
            bf16x8 bsf = *reinterpret_cast<const bf16x8*>(&simB[(nt * 16 + la) * 72 + ks * 32 + lb * 8]);
            sva[t] = MFMA16(av, bsf, sva[t]);
        }
    }
#pragma unroll
    for (int ks = 0; ks < 4; ++ks) {
        bf16x8 ar = *reinterpret_cast<const bf16x8*>(relBv + (m * 16 + la) * 128 + ks * 32 + lb * 8);
#pragma unroll
        for (int t = 0; t < 2; ++t) {
            int nt = 2 * s + t;
            bf16x8 bp = *reinterpret_cast<const bf16x8*>(&Pb[(nt * 16 + la) * 136 + ks * 32 + lb * 8]);
            svea[t] = MFMA16(ar, bp, svea[t]);
        }
    }
    __builtin_amdgcn_s_setprio(0);
    // store sv -> qkP slice, sve -> vP slice + out-BN partial stats
    float st0[4] = {0, 0, 0, 0}, st1[4] = {0, 0, 0, 0}, st2[4] = {0, 0, 0, 0}, st3[4] = {0, 0, 0, 0};
#pragma unroll
    for (int t = 0; t < 2; ++t) {
        int i = (2 * s + t) * 16 + la;
        bool ok = i < 56;
#pragma unroll
        for (int r = 0; r < 4; ++r) {
            int c = m * 16 + lb * 4 + r;
            float va = sva[t][r], ve = svea[t][r];
            if (ok) {
                svdst[c * 56 + i] = f2bfbits(va);
                vHs  [c * 56 + i] = f2bfbits(ve);
                st0[r] += va; st1[r] += va * va; st2[r] += ve; st3[r] += ve * ve;
            }
        }
    }
#pragma unroll
    for (int r = 0; r < 4; ++r) {
#pragma unroll
        for (int mk = 1; mk < 16; mk <<= 1) {
            st0[r] += __shfl_xor(st0[r], mk);
            st1[r] += __shfl_xor(st1[r], mk);
            st2[r] += __shfl_xor(st2[r], mk);
            st3[r] += __shfl_xor(st3[r], mk);
        }
    }
    if (la == 0) {
#pragma unroll
        for (int r = 0; r < 4; ++r) {
            int c = m * 16 + lb * 4 + r;
            red[(0 * 64 + c) * 2 + s] = st0[r];
            red[(1 * 64 + c) * 2 + s] = st1[r];
            red[(2 * 64 + c) * 2 + s] = st2[r];
            red[(3 * 64 + c) * 2 + s] = st3[r];
        }
    }
    __syncthreads();
    if (tid < 64) {
        int c = tid, o2 = (g * 64 + c) * 2, bkt = blk & 7;
        atomicAdd(&osum[o2 * 8 + bkt],       red[(0 * 64 + c) * 2] + red[(0 * 64 + c) * 2 + 1]);
        atomicAdd(&osq [o2 * 8 + bkt],       red[(1 * 64 + c) * 2] + red[(1 * 64 + c) * 2 + 1]);
        atomicAdd(&osum[(o2 + 1) * 8 + bkt], red[(2 * 64 + c) * 2] + red[(2 * 64 + c) * 2 + 1]);
        atomicAdd(&osq [(o2 + 1) * 8 + bkt], red[(3 * 64 + c) * 2] + red[(3 * 64 + c) * 2 + 1]);
    }
}

__global__ __launch_bounds__(256) void k3b_coef(const float* __restrict__ osum, const float* __restrict__ osq,
                                                const float* __restrict__ go, const float* __restrict__ bo,
                                                float* __restrict__ a_c, float* __restrict__ b_c) {
    int o = blockIdx.x * 256 + threadIdx.x;
    float s = 0, s2 = 0;
#pragma unroll
    for (int k = 0; k < 8; ++k) { s += osum[o * 8 + k]; s2 += osq[o * 8 + k]; }
    float inv = 1.f / 50176.f;
    float mean = s * inv;
    float var = s2 * inv - mean * mean;
    float a = go[o] * rsqrtf(var + EPS);
    a_c[o] = a; b_c[o] = bo[o] - a * mean;
}

// ---------------- K4 ----------------
__global__ __launch_bounds__(256) void k4_out(const short* __restrict__ svq,
                                              const short* __restrict__ sve,
                                              const float* __restrict__ ao, const float* __restrict__ bo,
                                              float* __restrict__ out) {
    int blk = blockIdx.x;
    int oc = blk & 511, bt = blk >> 9;
    int b = bt >> 2, tt = bt & 3;
    int g = oc >> 6, c = oc & 63;
    __shared__ float tile[56][57];
    int tid = threadIdx.x;
    int o_sv = oc * 2, o_sve = oc * 2 + 1;
    float asv = ao[o_sv], bsv = bo[o_sv], asve = ao[o_sve], bsve = bo[o_sve];
    float badd = bsv + bsve;
    int nbase = (b * 4 + tt) * 56;
    for (int e = tid; e < 3136; e += 256) {
        int wq = e / 56, h = e - wq * 56;
        size_t idx = ((size_t)g * 50176 + (size_t)(nbase + wq) * 56) * 64 + c * 56 + h;
        tile[wq][h] = asv * bfbits2f(svq[idx]) + asve * bfbits2f(sve[idx]) + badd;
    }
    __syncthreads();
    size_t ob = ((size_t)(b * 512 + oc) * 4 + tt) * 3136;
    for (int e = tid; e < 3136; e += 256) {
        int h = e / 56, wq = e - h * 56;
        out[ob + h * 56 + wq] = tile[wq][h];
    }
}

extern "C" void kernel_launch(void* const* d_in, const int* in_sizes, int n_in,
                              void* d_out, int out_size, void* d_ws, size_t ws_size,
                              hipStream_t stream) {
    (void)in_sizes; (void)n_in; (void)out_size; (void)ws_size;
    const float* x     = (const float*)d_in[0];
    const float* w_qkv = (const float*)d_in[1];
    const float* g_qkv = (const float*)d_in[2];
    const float* b_qkv = (const float*)d_in[3];
    const float* rel   = (const float*)d_in[4];
    const float* g_sim = (const float*)d_in[5];
    const float* b_sim = (const float*)d_in[6];
    const float* g_out = (const float*)d_in[7];
    const float* b_out = (const float*)d_in[8];
    float* ws  = (float*)d_ws;
    float* out = (float*)d_out;
    short* qkP = (short*)((char*)d_ws + 131072);
    short* vP  = (short*)((char*)d_ws + 51511296);
    bf*    xbt = (bf*)d_out;
    bf*    wb  = (bf*)((char*)d_out + 51380224);
    short* relTq = (short*)((char*)d_out + 73400320);
    short* relTk = relTq + 3584;
    short* relBv = relTk + 3584;

    hipMemsetAsync(ws, 0, WS_ZERO_END * sizeof(float), stream);
    k0_transpose<<<896, 256, 0, stream>>>(x, xbt);
    kw_conv<<<512, 256, 0, stream>>>(w_qkv, wb);
    kprep<<<46, 256, 0, stream>>>(rel, relTq, relTk, relBv);
    k1_mfma<<<dim3(8, 448), 256, 0, stream>>>(xbt, wb, qkP, vP, ws + WS_QSUM, ws + WS_QSQ);
    k1b_coef<<<4, 256, 0, stream>>>(ws + WS_QSUM, ws + WS_QSQ, g_qkv, b_qkv,
                                    ws + WS_AQKV, ws + WS_BQKV);
    kbn2<<<7168, 512, 0, stream>>>(qkP, vP, ws + WS_AQKV, ws + WS_BQKV,
                                   relTq, relTk, ws + WS_SIMSUM, ws + WS_SIMSQ);
    k2b_coef<<<1, 64, 0, stream>>>(ws + WS_SIMSUM, ws + WS_SIMSQ, g_sim, b_sim,
                                   ws + WS_ASIM, ws + WS_BSIM);
    k3_mfma<<<7168, 512, 0, stream>>>(relTq, relTk, relBv, qkP, vP,
                                      ws + WS_ASIM, ws + WS_BSIM,
                                      ws + WS_OUTSUM, ws + WS_OUTSQ);
    k3b_coef<<<4, 256, 0, stream>>>(ws + WS_OUTSUM, ws + WS_OUTSQ, g_out, b_out,
                                    ws + WS_AOUT, ws + WS_BOUT);
    k4_out<<<8192, 256, 0, stream>>>(qkP, vP, ws + WS_AOUT, ws + WS_BOUT, out);
}